// Round 16
// baseline (35.547 us; speedup 1.0000x reference)
//
#include <hip/hip_runtime.h>
#include <math.h>

#define TAIL_B 20.0f
#define BATCH 16384
#define NELEM (BATCH * 512)   // 8,388,608 elements per output tensor
#define ROWS_PB 32            // rows per block -> 512 blocks = 2 per CU (one round)
#define LDS_BYTES 69632       // cumh[512][17] + dk[512][17] f32

typedef float vf4 __attribute__((ext_vector_type(4)));

// Dynamic LDS layout (float offsets), stride 17 (odd -> conflict-free gathers):
//   cumh [512][17] @ 0      knot y
//   dk   [512][17] @ 8704   derivatives at knots, dk[0]=dk[16]=1
__global__ __launch_bounds__(1024, 8) void rqs_fused(
    const float* __restrict__ x, const float* __restrict__ W,
    const float* __restrict__ H, const float* __restrict__ D,
    float* __restrict__ out)
{
    extern __shared__ float s[];
    float* sCH = s;
    float* sDK = s + 8704;

    const int tid   = threadIdx.x;
    const int col   = tid & 511;          // = gi; contiguous across the block
    const int rsub  = tid >> 9;           // 0..1
    const int rbase = blockIdx.x * ROWS_PB + rsub * 16;  // 16 rows per thread

    // ---- chunk-0 prefetch (in flight across setup) ----
    float xA[4], xB[4];
#pragma unroll
    for (int i = 0; i < 4; ++i)
        xA[i] = x[(rbase + i) * 512 + col];

    // ---- per-thread width softmax: interior knots -> kr[15] registers ----
    float kr[15];
    {
        const float* Wg = W + col * 16;
        vf4 a = *reinterpret_cast<const vf4*>(Wg);
        vf4 b = *reinterpret_cast<const vf4*>(Wg + 4);
        vf4 c = *reinterpret_cast<const vf4*>(Wg + 8);
        vf4 d = *reinterpret_cast<const vf4*>(Wg + 12);
        float e[16] = {a.x, a.y, a.z, a.w, b.x, b.y, b.z, b.w,
                       c.x, c.y, c.z, c.w, d.x, d.y, d.z, d.w};
        float mw = e[0];
#pragma unroll
        for (int k = 1; k < 16; ++k) mw = fmaxf(mw, e[k]);
        float sum = 0.0f;
#pragma unroll
        for (int k = 0; k < 16; ++k) { e[k] = __expf(e[k] - mw); sum += e[k]; }
        float scw = (2.0f * TAIL_B) * __builtin_amdgcn_rcpf(sum);
        float run = 0.0f;
#pragma unroll
        for (int k = 0; k < 15; ++k) { run += e[k]; kr[k] = -TAIL_B + run * scw; }
    }

    // ---- prologue: H softmax + D softplus into LDS (2 threads/col) ----
    {
        const int c    = tid >> 1;        // 0..511
        const int half = tid & 1;         // bins 8*half .. 8*half+7
        const float* Hg = H + c * 16 + half * 8;
        vf4 ha = *reinterpret_cast<const vf4*>(Hg);
        vf4 hb = *reinterpret_cast<const vf4*>(Hg + 4);

        float mh = fmaxf(fmaxf(fmaxf(ha.x, ha.y), fmaxf(ha.z, ha.w)),
                         fmaxf(fmaxf(hb.x, hb.y), fmaxf(hb.z, hb.w)));
        mh = fmaxf(mh, __shfl_xor(mh, 1));

        float eh[8] = {__expf(ha.x - mh), __expf(ha.y - mh), __expf(ha.z - mh), __expf(ha.w - mh),
                       __expf(hb.x - mh), __expf(hb.y - mh), __expf(hb.z - mh), __expf(hb.w - mh)};
        float sh = 0.0f;
#pragma unroll
        for (int j = 0; j < 8; ++j) sh += eh[j];
        float shp = __shfl_xor(sh, 1);
        float sch = (2.0f * TAIL_B) / (sh + shp);
        float ah  = half ? shp : 0.0f;    // exclusive prefix from partner

        const float* Dg = D + c * 15;
        float* ch = sCH + c * 17;
        float* dk = sDK + c * 17;
        if (!half) { ch[0] = -TAIL_B; dk[0] = 1.0f; }

#pragma unroll
        for (int j = 0; j < 8; ++j) {
            ah += eh[j];
            int t = half * 8 + j + 1;     // knot index 1..16
            ch[t] = -TAIL_B + ah * sch;
            float dv = 1.0f;
            if (t < 16) {
                float v = Dg[t - 1];      // fast stable softplus
                dv = fmaxf(v, 0.0f) + __logf(1.0f + __expf(-fabsf(v)));
            }
            dk[t] = dv;
        }
    }
    __syncthreads();

    auto eval1 = [&](float xx, float& z, float& ld) {
        bool  inside = (xx >= -TAIL_B) && (xx <= TAIL_B);
        float xc = fminf(fmaxf(xx, -TAIL_B), TAIL_B);

        // register bin search + k0/k1 extraction (cndmask ladders, no LDS)
        int   idx = 0;
        float k0 = -TAIL_B, k1 = TAIL_B;
#pragma unroll
        for (int t = 0; t < 15; ++t) {
            bool c = xc >= kr[t];
            idx += c ? 1 : 0;
            k0 = c ? kr[t] : k0;
        }
#pragma unroll
        for (int t = 14; t >= 0; --t)
            k1 = (xc < kr[t]) ? kr[t] : k1;

        int p = col * 17 + idx;
        float ch0 = sCH[p], ch1 = sCH[p + 1];
        float d0  = sDK[p], d1  = sDK[p + 1];

        float invw  = __builtin_amdgcn_rcpf(k1 - k0);
        float hh    = ch1 - ch0;
        float de    = hh * invw;
        float theta = (xc - k0) * invw;
        float omt   = 1.0f - theta;
        float tt    = theta * omt;
        float denom = de + (d0 + d1 - 2.0f * de) * tt;
        float rden  = __builtin_amdgcn_rcpf(denom);
        float numer = hh * (de * theta * theta + d0 * tt);
        float zin   = ch0 + numer * rden;
        float dnum  = de * de * (d1 * theta * theta + 2.0f * de * tt + d0 * omt * omt);
        float ldin  = 0.6931471805599453f * __log2f(dnum * rden * rden);

        z  = inside ? zin : xx;
        ld = inside ? ldin : 0.0f;
    };

    auto compute4 = [&](const float (&xb)[4], int r0) {
#pragma unroll
        for (int i = 0; i < 4; ++i) {
            float z, ld;
            eval1(xb[i], z, ld);
            int addr = (r0 + i) * 512 + col;
            __builtin_nontemporal_store(z,  out + addr);
            __builtin_nontemporal_store(ld, out + NELEM + addr);
        }
    };

    // software pipeline over 4 chunks of 4 rows
#pragma unroll
    for (int i = 0; i < 4; ++i) xB[i] = x[(rbase + 4 + i) * 512 + col];
    compute4(xA, rbase);

#pragma unroll
    for (int i = 0; i < 4; ++i) xA[i] = x[(rbase + 8 + i) * 512 + col];
    compute4(xB, rbase + 4);

#pragma unroll
    for (int i = 0; i < 4; ++i) xB[i] = x[(rbase + 12 + i) * 512 + col];
    compute4(xA, rbase + 8);

    compute4(xB, rbase + 12);
}

extern "C" void kernel_launch(void* const* d_in, const int* in_sizes, int n_in,
                              void* d_out, int out_size, void* d_ws, size_t ws_size,
                              hipStream_t stream)
{
    const float* x = (const float*)d_in[0];
    const float* W = (const float*)d_in[1];
    const float* H = (const float*)d_in[2];
    const float* D = (const float*)d_in[3];
    float* out = (float*)d_out;

    hipFuncSetAttribute(reinterpret_cast<const void*>(&rqs_fused),
                        hipFuncAttributeMaxDynamicSharedMemorySize, LDS_BYTES);

    rqs_fused<<<BATCH / ROWS_PB, 1024, LDS_BYTES, stream>>>(x, W, H, D, out);
}

// Round 17
// 26.424 us; speedup vs baseline: 1.3453x; 1.3453x over previous
//
#include <hip/hip_runtime.h>
#include <math.h>

#define TAIL_B 20.0f
#define BATCH 16384
#define NELEM (BATCH * 512)   // 8,388,608 elements per output tensor
#define ROWS_PB 64            // rows per block -> 256 blocks = 1 per CU
#define LDS_BYTES 104448      // 3 tables * 512 cols * 17 * 4B

typedef float vf4 __attribute__((ext_vector_type(4)));

// Dynamic LDS layout (floats), stride 17 (odd -> conflict-free lane gathers):
//   cumw [512][17] @ 0       knot x
//   cumh [512][17] @ 8704    knot y
//   dk   [512][17] @ 17408   derivatives at knots, dk[0]=dk[16]=1
__global__ __launch_bounds__(1024, 4) void rqs_fused(
    const float* __restrict__ x, const float* __restrict__ W,
    const float* __restrict__ H, const float* __restrict__ D,
    float* __restrict__ out)
{
    extern __shared__ float s[];
    float* sCW = s;
    float* sCH = s + 8704;
    float* sDK = s + 17408;

    const int tid   = threadIdx.x;
    const int col   = tid & 511;          // = gi; contiguous across the block
    const int rsub  = tid >> 9;           // 0..1
    const int rbase = blockIdx.x * ROWS_PB + rsub * 32;

    // ---- batch A prefetch (rows rbase+0..7), issued before prologue ----
    float xbA[8], xbB[8];
#pragma unroll
    for (int i = 0; i < 8; ++i)
        xbA[i] = x[(rbase + i) * 512 + col];

    // ---- prologue: 2 threads per column, runs ONCE per CU ----
    {
        const int c    = tid >> 1;        // 0..511 (column this thread builds)
        const int half = tid & 1;         // bins 8*half .. 8*half+7
        const float* Wg = W + c * 16 + half * 8;
        const float* Hg = H + c * 16 + half * 8;

        vf4 wa = *reinterpret_cast<const vf4*>(Wg);
        vf4 wb = *reinterpret_cast<const vf4*>(Wg + 4);
        vf4 ha = *reinterpret_cast<const vf4*>(Hg);
        vf4 hb = *reinterpret_cast<const vf4*>(Hg + 4);

        float mw = fmaxf(fmaxf(fmaxf(wa.x, wa.y), fmaxf(wa.z, wa.w)),
                         fmaxf(fmaxf(wb.x, wb.y), fmaxf(wb.z, wb.w)));
        float mh = fmaxf(fmaxf(fmaxf(ha.x, ha.y), fmaxf(ha.z, ha.w)),
                         fmaxf(fmaxf(hb.x, hb.y), fmaxf(hb.z, hb.w)));
        mw = fmaxf(mw, __shfl_xor(mw, 1));
        mh = fmaxf(mh, __shfl_xor(mh, 1));

        float ew[8] = {__expf(wa.x - mw), __expf(wa.y - mw), __expf(wa.z - mw), __expf(wa.w - mw),
                       __expf(wb.x - mw), __expf(wb.y - mw), __expf(wb.z - mw), __expf(wb.w - mw)};
        float eh[8] = {__expf(ha.x - mh), __expf(ha.y - mh), __expf(ha.z - mh), __expf(ha.w - mh),
                       __expf(hb.x - mh), __expf(hb.y - mh), __expf(hb.z - mh), __expf(hb.w - mh)};

        float sw = 0.0f, sh = 0.0f;
#pragma unroll
        for (int j = 0; j < 8; ++j) { sw += ew[j]; sh += eh[j]; }
        float swp = __shfl_xor(sw, 1), shp = __shfl_xor(sh, 1);
        float scw = (2.0f * TAIL_B) / (sw + swp);
        float sch = (2.0f * TAIL_B) / (sh + shp);

        float aw = half ? swp : 0.0f;     // exclusive prefix from partner
        float ah = half ? shp : 0.0f;

        const float* Dg = D + c * 15;
        float* cw = sCW + c * 17;
        float* ch = sCH + c * 17;
        float* dk = sDK + c * 17;
        if (!half) { cw[0] = -TAIL_B; ch[0] = -TAIL_B; dk[0] = 1.0f; }

#pragma unroll
        for (int j = 0; j < 8; ++j) {
            aw += ew[j]; ah += eh[j];
            int t = half * 8 + j + 1;     // knot index 1..16
            cw[t] = -TAIL_B + aw * scw;
            ch[t] = -TAIL_B + ah * sch;
            float dv = 1.0f;
            if (t < 16) {
                float v = Dg[t - 1];      // fast stable softplus
                dv = fmaxf(v, 0.0f) + __logf(1.0f + __expf(-fabsf(v)));
            }
            dk[t] = dv;
        }
    }
    __syncthreads();

    // 15 interior knots -> registers (bank = (17*col + t) % 32, conflict-free)
    float kr[15];
#pragma unroll
    for (int t = 0; t < 15; ++t) kr[t] = sCW[col * 17 + 1 + t];

    auto compute8 = [&](const float (&xb)[8], int r0) {
#pragma unroll
        for (int i = 0; i < 8; ++i) {
            float xx = xb[i];
            bool  inside = (xx >= -TAIL_B) && (xx <= TAIL_B);
            float xc = fminf(fmaxf(xx, -TAIL_B), TAIL_B);

            int idx = 0;
#pragma unroll
            for (int t = 0; t < 15; ++t) idx += (xc >= kr[t]) ? 1 : 0;

            int p = col * 17 + idx;
            float k0  = sCW[p], k1  = sCW[p + 1];
            float ch0 = sCH[p], ch1 = sCH[p + 1];
            float d0  = sDK[p], d1  = sDK[p + 1];

            float invw  = __builtin_amdgcn_rcpf(k1 - k0);
            float hh    = ch1 - ch0;
            float de    = hh * invw;
            float theta = (xc - k0) * invw;
            float omt   = 1.0f - theta;
            float tt    = theta * omt;
            float denom = de + (d0 + d1 - 2.0f * de) * tt;
            float rden  = __builtin_amdgcn_rcpf(denom);
            float numer = hh * (de * theta * theta + d0 * tt);
            float zin   = ch0 + numer * rden;
            float dnum  = de * de * (d1 * theta * theta + 2.0f * de * tt + d0 * omt * omt);
            float ldin  = 0.6931471805599453f * __log2f(dnum * rden * rden);

            float z  = inside ? zin : xx;
            float ld = inside ? ldin : 0.0f;

            int addr = (r0 + i) * 512 + col;
            __builtin_nontemporal_store(z,  out + addr);
            __builtin_nontemporal_store(ld, out + NELEM + addr);
        }
    };

    // software pipeline: issue next 8-row batch before computing current
#pragma unroll
    for (int i = 0; i < 8; ++i) xbB[i] = x[(rbase + 8 + i) * 512 + col];
    compute8(xbA, rbase);

#pragma unroll
    for (int i = 0; i < 8; ++i) xbA[i] = x[(rbase + 16 + i) * 512 + col];
    compute8(xbB, rbase + 8);

#pragma unroll
    for (int i = 0; i < 8; ++i) xbB[i] = x[(rbase + 24 + i) * 512 + col];
    compute8(xbA, rbase + 16);

    compute8(xbB, rbase + 24);
}

extern "C" void kernel_launch(void* const* d_in, const int* in_sizes, int n_in,
                              void* d_out, int out_size, void* d_ws, size_t ws_size,
                              hipStream_t stream)
{
    const float* x = (const float*)d_in[0];
    const float* W = (const float*)d_in[1];
    const float* H = (const float*)d_in[2];
    const float* D = (const float*)d_in[3];
    float* out = (float*)d_out;

    hipFuncSetAttribute(reinterpret_cast<const void*>(&rqs_fused),
                        hipFuncAttributeMaxDynamicSharedMemorySize, LDS_BYTES);

    rqs_fused<<<BATCH / ROWS_PB, 1024, LDS_BYTES, stream>>>(x, W, H, D, out);
}